// Round 13
// baseline (406.207 us; speedup 1.0000x reference)
//
#include <hip/hip_runtime.h>
#include <cstdint>
#include <cstddef>

#define N_NODESC 50000
#define N_PAD    50048   // 391 * 128
#define N_EDGESC 600000
#define N_GRAPHSC 64
#define D_HIDC   128
#define D_LATC   64
#define D_GS     512     // G = [mean, max, min, std] (h section read from h directly)
#define D_WROW   1664    // transposed W row length (13*128)

typedef unsigned short u16;
typedef unsigned int   u32;

typedef _Float16 f16x8 __attribute__((ext_vector_type(8)));
typedef _Float16 f16x2 __attribute__((ext_vector_type(2)));
typedef float    f32x4 __attribute__((ext_vector_type(4)));
typedef float    f32x2 __attribute__((ext_vector_type(2)));

__device__ __forceinline__ u16 f2h(float f) {
    return __builtin_bit_cast(u16, (_Float16)f);
}
__device__ __forceinline__ float h2f(u16 u) {
    return (float)__builtin_bit_cast(_Float16, u);
}
__device__ __forceinline__ u32 pkrtz(float a, float b) {
    return __builtin_bit_cast(u32, __builtin_amdgcn_cvt_pkrtz(a, b));
}

// packed f32 ops (force v_pk_* codegen; pure-VALU asm, no ordering hazard)
__device__ __forceinline__ f32x2 pk_add(f32x2 a, f32x2 b) {
    f32x2 d;
    asm("v_pk_add_f32 %0, %1, %2" : "=v"(d) : "v"(a), "v"(b));
    return d;
}
__device__ __forceinline__ f32x2 pk_fma(f32x2 a, f32x2 b, f32x2 c) {
    f32x2 d;
    asm("v_pk_fma_f32 %0, %1, %2, %3" : "=v"(d) : "v"(a), "v"(b), "v"(c));
    return d;
}

__device__ __forceinline__ void gll16(void* lds, const void* g) {
    // async global->LDS, 16B per lane; HW dest = wave-uniform base + lane*16
    __builtin_amdgcn_global_load_lds(
        (const __attribute__((address_space(1))) void*)g,
        (__attribute__((address_space(3))) void*)lds, 16, 0, 0);
}

// ---------------- fused setup ----------------
// block ranges: [0,ZB) zero | [ZB,ZB+12500) x2h | next 78 wconv(LDS) | last goff
__global__ void __launch_bounds__(256) k_setup(
        const float* __restrict__ x, const float* __restrict__ W0,
        const float* __restrict__ W1, const float* __restrict__ W2,
        const int* __restrict__ batch,
        u16* __restrict__ h, u16* __restrict__ Wt,
        int* __restrict__ zero_base, int nz, int ZB, int* __restrict__ goff) {
    __shared__ u16 lt[64 * 128];   // 16 KB transpose tile (wconv blocks only)
    int b = blockIdx.x;
    int t = threadIdx.x;
    if (b < ZB) {
        int i = b * 256 + t;
        if (i < nz) zero_base[i] = 0;
        return;
    }
    b -= ZB;
    if (b < 12500) {                       // x -> fp16 (2 elems/thread)
        int i = b * 256 + t;
        float2 v = ((const float2*)x)[i];
        ((u32*)h)[i] = (u32)f2h(v.x) | ((u32)f2h(v.y) << 16);
        return;
    }
    b -= 12500;
    if (b < 78) {                          // W transpose+cast, LDS-tiled
        int which = b / 26;
        int k0 = (b % 26) * 64;
        const float* W = (which == 0) ? W0 : (which == 1) ? W1 : W2;
        const float* src = W + (size_t)k0 * D_HIDC;
        for (int i = t; i < 64 * 128; i += 256)
            lt[i] = f2h(src[i]);           // lt[kk*128 + j]
        __syncthreads();
        int j = t & 127, kh = t >> 7;
        u16* dst = Wt + (size_t)which * D_WROW * D_HIDC
                      + (size_t)j * D_WROW + k0 + kh * 32;
        #pragma unroll
        for (int c = 0; c < 4; c++) {
            int kb = kh * 32 + c * 8;
            u32 p0 = (u32)lt[(kb + 0) * 128 + j] | ((u32)lt[(kb + 1) * 128 + j] << 16);
            u32 p1 = (u32)lt[(kb + 2) * 128 + j] | ((u32)lt[(kb + 3) * 128 + j] << 16);
            u32 p2 = (u32)lt[(kb + 4) * 128 + j] | ((u32)lt[(kb + 5) * 128 + j] << 16);
            u32 p3 = (u32)lt[(kb + 6) * 128 + j] | ((u32)lt[(kb + 7) * 128 + j] << 16);
            uint4 v; v.x = p0; v.y = p1; v.z = p2; v.w = p3;
            *(uint4*)(dst + c * 8) = v;
        }
        return;
    }
    // goff via binary search over sorted batch
    int g = t;
    if (g <= N_GRAPHSC) {
        int lo = 0, hi = N_NODESC;
        while (lo < hi) {
            int mid = (lo + hi) >> 1;
            if (batch[mid] < g) lo = mid + 1; else hi = mid;
        }
        goff[g] = lo;
    }
}

__global__ void k_count(const int* __restrict__ dst, int* __restrict__ deg) {
    int e = blockIdx.x * 256 + threadIdx.x;
    if (e < N_EDGESC) atomicAdd(&deg[dst[e]], 1);
}

// 196 blocks: per-block int sum -> bsum, per-block logf sum -> lsum
__global__ void __launch_bounds__(256) k_scan_part(
        const int* __restrict__ deg, int* __restrict__ bsum,
        float* __restrict__ lsum) {
    __shared__ int s[256];
    __shared__ float ls[256];
    int idx = blockIdx.x * 256 + threadIdx.x;
    int v = (idx < N_NODESC) ? deg[idx] : 0;
    s[threadIdx.x] = v;
    ls[threadIdx.x] = (idx < N_NODESC) ? logf((float)v + 1.0f) : 0.0f;
    __syncthreads();
    for (int o = 128; o > 0; o >>= 1) {
        if (threadIdx.x < o) {
            s[threadIdx.x] += s[threadIdx.x + o];
            ls[threadIdx.x] += ls[threadIdx.x + o];
        }
        __syncthreads();
    }
    if (threadIdx.x == 0) { bsum[blockIdx.x] = s[0]; lsum[blockIdx.x] = ls[0]; }
}

// 1 block: exclusive-scan bsum (196 entries) + reduce lsum -> delta
__global__ void __launch_bounds__(256) k_scan_block(
        int* __restrict__ bsum, const float* __restrict__ lsum,
        float* __restrict__ delta_p) {
    __shared__ int s[256];
    __shared__ float ls[256];
    int t = threadIdx.x;
    int v = (t < 196) ? bsum[t] : 0;
    s[t] = v;
    ls[t] = (t < 196) ? lsum[t] : 0.0f;
    __syncthreads();
    for (int o = 1; o < 256; o <<= 1) {
        int add = (t >= o) ? s[t - o] : 0;
        __syncthreads();
        s[t] += add;
        __syncthreads();
    }
    if (t < 196) bsum[t] = s[t] - v;   // exclusive
    for (int o = 128; o > 0; o >>= 1) {
        if (t < o) ls[t] += ls[t + o];
        __syncthreads();
    }
    if (t == 0) delta_p[0] = ls[0] * (1.0f / (float)N_NODESC);
}

// 196 blocks: block-local exclusive scan + block offset -> row_off.
// Also emits the per-node PNA scaler table amat[n] = {am, at}
// (delta_p is ready: k_scan_block runs before this kernel).
__global__ void __launch_bounds__(256) k_scan_final(
        const int* __restrict__ deg, const int* __restrict__ bsum,
        const float* __restrict__ delta_p,
        int* __restrict__ row_off, float2* __restrict__ amat) {
    __shared__ int s[256];
    int t = threadIdx.x;
    int idx = blockIdx.x * 256 + t;
    int v = (idx < N_NODESC) ? deg[idx] : 0;
    s[t] = v; __syncthreads();
    for (int o = 1; o < 256; o <<= 1) {
        int add = (t >= o) ? s[t - o] : 0;
        __syncthreads();
        s[t] += add;
        __syncthreads();
    }
    int excl = s[t] - v + bsum[blockIdx.x];
    if (idx < N_NODESC) row_off[idx] = excl;
    if (idx == 0) row_off[N_NODESC] = N_EDGESC;
    if (idx < N_PAD) {
        float delta = delta_p[0];
        float logd = logf((float)v + 1.0f);   // v=0 for pad nodes
        float2 aa;
        aa.x = logd / delta;                   // am
        aa.y = delta / fmaxf(logd, 1e-5f);     // at (pad: large, discarded)
        amat[idx] = aa;
    }
}

// csr stores PRE-SCALED byte offsets (src*256) so gathers are base+u32 voffset
__global__ void k_fill_csr(const int* __restrict__ src, const int* __restrict__ dst,
                           const int* __restrict__ row_off, int* __restrict__ cursor,
                           int* __restrict__ csr_src) {
    int e = blockIdx.x * 256 + threadIdx.x;
    if (e < N_EDGESC) {
        int d = dst[e];
        int pos = row_off[d] + atomicAdd(&cursor[d], 1);
        csr_src[pos] = src[e] << 8;   // byte offset into h (128 * 2B per row)
    }
}

// ---------------- per-layer kernels ----------------

// R7 agg (verified best; R10 uint4-index and R11 16-lane variants both
// null/negative -> gather-completion-latency floor ~33us): one node per
// half-wave + 8-deep gather pipeline, rotated scalar index prefetch,
// packed f32 sum/sq, exact fp16 packed min/max.
__global__ void __launch_bounds__(256) k_aggregate(
        const u16* __restrict__ h, const int* __restrict__ row_off,
        const int* __restrict__ csr_src, u16* __restrict__ G) {
    int lane = threadIdx.x & 63;
    int half = lane >> 5, l32 = lane & 31;
    int n = blockIdx.x * 8 + ((threadIdx.x >> 6) << 1) + half;
    if (n >= N_NODESC) return;
    int c4 = 4 * l32;
    u32 c8 = 8u * (u32)l32;
    const char* h8 = (const char*)h;
    int beg = row_off[n], end = row_off[n + 1];
    const _Float16 NEG = (_Float16)(-65504.0f), POS = (_Float16)(65504.0f);
    f32x2 s01 = {0.f, 0.f}, s23 = {0.f, 0.f};
    f32x2 q01 = {0.f, 0.f}, q23 = {0.f, 0.f};
    f16x2 mx01 = {NEG, NEG}, mx23 = {NEG, NEG};
    f16x2 mn01 = {POS, POS}, mn23 = {POS, POS};

    #define PROC(u) { \
        f16x2 p01 = __builtin_bit_cast(f16x2, (u).x); \
        f16x2 p23 = __builtin_bit_cast(f16x2, (u).y); \
        f32x2 c01 = __builtin_convertvector(p01, f32x2); \
        f32x2 c23 = __builtin_convertvector(p23, f32x2); \
        s01 = pk_add(s01, c01); s23 = pk_add(s23, c23); \
        q01 = pk_fma(c01, c01, q01); q23 = pk_fma(c23, c23, q23); \
        mx01 = __builtin_elementwise_max(mx01, p01); \
        mx23 = __builtin_elementwise_max(mx23, p23); \
        mn01 = __builtin_elementwise_min(mn01, p01); \
        mn23 = __builtin_elementwise_min(mn23, p23); }
    #define GTH(e) (*(const uint2*)(h8 + ((e) + c8)))

    int i = beg;
    if (i + 8 <= end) {
        u32 e0 = (u32)csr_src[i],     e1 = (u32)csr_src[i + 1];
        u32 e2 = (u32)csr_src[i + 2], e3 = (u32)csr_src[i + 3];
        u32 e4 = (u32)csr_src[i + 4], e5 = (u32)csr_src[i + 5];
        u32 e6 = (u32)csr_src[i + 6], e7 = (u32)csr_src[i + 7];
        while (i + 16 <= end) {
            uint2 u0 = GTH(e0), u1 = GTH(e1), u2 = GTH(e2), u3 = GTH(e3);
            uint2 u4 = GTH(e4), u5 = GTH(e5), u6 = GTH(e6), u7 = GTH(e7);
            e0 = (u32)csr_src[i + 8];  e1 = (u32)csr_src[i + 9];
            e2 = (u32)csr_src[i + 10]; e3 = (u32)csr_src[i + 11];
            e4 = (u32)csr_src[i + 12]; e5 = (u32)csr_src[i + 13];
            e6 = (u32)csr_src[i + 14]; e7 = (u32)csr_src[i + 15];
            PROC(u0); PROC(u1); PROC(u2); PROC(u3);
            PROC(u4); PROC(u5); PROC(u6); PROC(u7);
            i += 8;
        }
        uint2 u0 = GTH(e0), u1 = GTH(e1), u2 = GTH(e2), u3 = GTH(e3);
        uint2 u4 = GTH(e4), u5 = GTH(e5), u6 = GTH(e6), u7 = GTH(e7);
        PROC(u0); PROC(u1); PROC(u2); PROC(u3);
        PROC(u4); PROC(u5); PROC(u6); PROC(u7);
        i += 8;
    }
    for (; i + 3 < end; i += 4) {
        u32 e0 = (u32)csr_src[i],     e1 = (u32)csr_src[i + 1];
        u32 e2 = (u32)csr_src[i + 2], e3 = (u32)csr_src[i + 3];
        uint2 u0 = GTH(e0), u1 = GTH(e1), u2 = GTH(e2), u3 = GTH(e3);
        PROC(u0); PROC(u1); PROC(u2); PROC(u3);
    }
    for (; i < end; ++i) {
        u32 e0 = (u32)csr_src[i];
        uint2 u0 = GTH(e0);
        PROC(u0);
    }
    #undef PROC
    #undef GTH

    int d = end - beg;
    float inv = 1.0f / fmaxf((float)d, 1.0f);
    f32x2 vinv = {inv, inv};
    f32x2 me01 = s01 * vinv, me23 = s23 * vinv;
    f32x2 qn01 = q01 * vinv, qn23 = q23 * vinv;
    f32x2 var01 = qn01 - me01 * me01;
    f32x2 var23 = qn23 - me23 * me23;
    const f32x2 z2 = {0.f, 0.f};
    var01 = __builtin_elementwise_max(var01, z2);
    var23 = __builtin_elementwise_max(var23, z2);
    float sd0 = sqrtf(var01.x + 1e-5f), sd1 = sqrtf(var01.y + 1e-5f);
    float sd2 = sqrtf(var23.x + 1e-5f), sd3 = sqrtf(var23.y + 1e-5f);

    u32 mep01 = pkrtz(me01.x, me01.y), mep23 = pkrtz(me23.x, me23.y);
    u32 sdp01 = pkrtz(sd0, sd1),       sdp23 = pkrtz(sd2, sd3);
    u32 mxb01 = __builtin_bit_cast(u32, mx01), mxb23 = __builtin_bit_cast(u32, mx23);
    u32 mnb01 = __builtin_bit_cast(u32, mn01), mnb23 = __builtin_bit_cast(u32, mn23);
    if (d == 0) { mxb01 = mxb23 = mnb01 = mnb23 = 0u; }

    u16* base = G + (size_t)n * D_GS;
    uint2 M; M.x = mep01; M.y = mep23;
    uint2 X; X.x = mxb01; X.y = mxb23;
    uint2 N_; N_.x = mnb01; N_.y = mnb23;
    uint2 S; S.x = sdp01; S.y = sdp23;
    *(uint2*)(base + c4)       = M;
    *(uint2*)(base + 128 + c4) = X;
    *(uint2*)(base + 256 + c4) = N_;
    *(uint2*)(base + 384 + c4) = S;
}

// h_out[n][j] = relu(bias + B*W1 + am*(S*W2) + at*(S*W3)) over logical B = [h|G]
// R13: j-SPLIT of the R4 structure -- each block computes 64 of 128 output
// cols for a 128-node tile (grid 782 = 391 tiles x 2 halves; adjacent pair
// shares the L2-hot B panel). LDS = 3x8 KB A-halves + 16 KB Bt = 40 KB ->
// 3 blocks/CU ((256,3): VGPR cap 170 >> halved 64-reg acc file; R9's spill
// trap avoided). Mechanism: per-block vmcnt(0) barrier drains overlap the
// other 2 co-resident blocks' MFMA phases (m114, tripled depth). Addressing
// is the R4 swizzle verbatim (row&7 algebra unchanged for 64-row tiles).
__global__ void __launch_bounds__(256, 3) k_gemm(
        const u16* __restrict__ hin, const u16* __restrict__ G,
        const u16* __restrict__ Wt,
        const float2* __restrict__ amat,
        const float* __restrict__ bias, u16* __restrict__ hout) {
    __shared__ _Float16 A1[64 * 64];    // 8 KB (W1 j-half)
    __shared__ _Float16 A2[64 * 64];    // 8 KB (W2 j-half)
    __shared__ _Float16 A3[64 * 64];    // 8 KB (W3 j-half)
    __shared__ _Float16 Bt[128 * 64];   // 16 KB (128-node B tile)
    const _Float16* Wf = (const _Float16*)Wt;
    const _Float16* Gf = (const _Float16*)G;
    const _Float16* Hf = (const _Float16*)hin;
    int bid = blockIdx.x;
    int n0 = (bid >> 1) * 128;
    int jh = (bid & 1) * 64;            // this block's output-col base
    int t = threadIdx.x;
    int w = t >> 6, lane = t & 63;
    int srow8 = lane >> 3, sslot = lane & 7;
    int stg = (sslot ^ srow8) * 8;      // swizzled source chunk offset
    int q4 = lane >> 4, r16 = lane & 15;
    int sx0 = (q4 ^ (lane & 7)) * 8;
    int sx1 = ((q4 + 4) ^ (lane & 7)) * 8;
    int col = lane & 15;

    float atv[8];
    _Float16 amh[8];
    #pragma unroll
    for (int nt = 0; nt < 8; nt++) {
        float2 aa = amat[n0 + nt * 16 + col];
        amh[nt] = (_Float16)aa.x;
        atv[nt] = aa.y;
    }

    f32x4 acc[8], ac3[8];
    #pragma unroll
    for (int b = 0; b < 8; b++) {
        acc[b] = (f32x4){0.f, 0.f, 0.f, 0.f};
        ac3[b] = (f32x4){0.f, 0.f, 0.f, 0.f};
    }

    for (int ki = 0; ki < 10; ki++) {
        int k0 = ki * 64;
        bool sreg = (k0 >= 128);
        __syncthreads();
        #pragma unroll
        for (int r = 0; r < 2; r++) {
            int rr = r * 4 + w;         // 8 stage-calls cover 64 j-rows
            const _Float16* wrow = Wf + (size_t)(jh + rr * 8 + srow8) * D_WROW;
            gll16(&A1[rr * 512], wrow + k0 + stg);
        }
        if (sreg) {
            #pragma unroll
            for (int r = 0; r < 2; r++) {
                int rr = r * 4 + w;
                const _Float16* wrow = Wf + (size_t)(jh + rr * 8 + srow8) * D_WROW;
                gll16(&A2[rr * 512], wrow + 512 + k0 + stg);
                gll16(&A3[rr * 512], wrow + 1024 + k0 + stg);
            }
        }
        #pragma unroll
        for (int q = 0; q < 4; q++) {
            int rr = q * 4 + w;
            int row = n0 + rr * 8 + srow8;
            const _Float16* bsrc = (!sreg)
                ? Hf + (size_t)row * D_HIDC + k0 + stg
                : Gf + (size_t)row * D_GS + (k0 - 128) + stg;
            gll16(&Bt[rr * 512], bsrc);
        }
        __syncthreads();
        f16x8 a00 = *(const f16x8*)&A1[(w * 16 + r16) * 64 + sx0];
        f16x8 a01 = *(const f16x8*)&A1[(w * 16 + r16) * 64 + sx1];
        if (!sreg) {
            #pragma unroll
            for (int nt = 0; nt < 8; nt++) {
                f16x8 b0 = *(const f16x8*)&Bt[(nt * 16 + r16) * 64 + sx0];
                f16x8 b1 = *(const f16x8*)&Bt[(nt * 16 + r16) * 64 + sx1];
                acc[nt] = __builtin_amdgcn_mfma_f32_16x16x32_f16(a00, b0, acc[nt], 0, 0, 0);
                acc[nt] = __builtin_amdgcn_mfma_f32_16x16x32_f16(a01, b1, acc[nt], 0, 0, 0);
            }
        } else {
            f16x8 w2a0 = *(const f16x8*)&A2[(w * 16 + r16) * 64 + sx0];
            f16x8 w2a1 = *(const f16x8*)&A2[(w * 16 + r16) * 64 + sx1];
            f16x8 w3a0 = *(const f16x8*)&A3[(w * 16 + r16) * 64 + sx0];
            f16x8 w3a1 = *(const f16x8*)&A3[(w * 16 + r16) * 64 + sx1];
            #pragma unroll
            for (int nt = 0; nt < 8; nt++) {
                f16x8 b0 = *(const f16x8*)&Bt[(nt * 16 + r16) * 64 + sx0];
                f16x8 b1 = *(const f16x8*)&Bt[(nt * 16 + r16) * 64 + sx1];
                f16x8 bm0 = b0 * amh[nt];
                f16x8 bm1 = b1 * amh[nt];
                acc[nt] = __builtin_amdgcn_mfma_f32_16x16x32_f16(a00, b0, acc[nt], 0, 0, 0);
                acc[nt] = __builtin_amdgcn_mfma_f32_16x16x32_f16(a01, b1, acc[nt], 0, 0, 0);
                acc[nt] = __builtin_amdgcn_mfma_f32_16x16x32_f16(w2a0, bm0, acc[nt], 0, 0, 0);
                acc[nt] = __builtin_amdgcn_mfma_f32_16x16x32_f16(w2a1, bm1, acc[nt], 0, 0, 0);
                ac3[nt] = __builtin_amdgcn_mfma_f32_16x16x32_f16(w3a0, b0, ac3[nt], 0, 0, 0);
                ac3[nt] = __builtin_amdgcn_mfma_f32_16x16x32_f16(w3a1, b1, ac3[nt], 0, 0, 0);
            }
        }
    }
    // D[row=(lane>>4)*4+reg][col=lane&15]; row -> j (within wave's 16), col -> node
    int rowq = q4 * 4;
    int jb = jh + w * 16 + rowq;
    #pragma unroll
    for (int nt = 0; nt < 8; nt++) {
        int node = n0 + nt * 16 + col;
        float at = atv[nt];
        f32x4 v = acc[nt], v3 = ac3[nt];
        ushort4 o;
        o.x = f2h(fmaxf(v.x + at * v3.x + bias[jb], 0.0f));
        o.y = f2h(fmaxf(v.y + at * v3.y + bias[jb + 1], 0.0f));
        o.z = f2h(fmaxf(v.z + at * v3.z + bias[jb + 2], 0.0f));
        o.w = f2h(fmaxf(v.w + at * v3.w + bias[jb + 3], 0.0f));
        *(ushort4*)&hout[(size_t)node * D_HIDC + jb] = o;
    }
}

// ---------------- epilogue kernels ----------------

__global__ void __launch_bounds__(256) k_pool(
        const u16* __restrict__ h, const int* __restrict__ goff,
        float* __restrict__ pooled) {
    __shared__ float sm[256];
    int g = blockIdx.x >> 2, s = blockIdx.x & 3;
    int gb = goff[g], ge = goff[g + 1];
    int len = ge - gb;
    int q = (len + 3) >> 2;
    int nb = gb + s * q;
    int ne = min(nb + q, ge);
    int t = threadIdx.x;
    int j = t & 127, half = t >> 7;
    float acc = 0.0f;
    for (int n = nb + half; n < ne; n += 2)
        acc += h2f(h[(size_t)n * D_HIDC + j]);
    sm[t] = acc; __syncthreads();
    if (t < 128) {
        float v = sm[t] + sm[t + 128];
        atomicAdd(&pooled[g * D_HIDC + j], v);
    }
}

// one block per graph; redundant mu/var recompute (pooled is tiny, L2-hot)
__global__ void __launch_bounds__(128) k_bn_fc(
        const float* __restrict__ pooled, const float* __restrict__ gamma,
        const float* __restrict__ beta, const float* __restrict__ fcW,
        const float* __restrict__ fcb, float* __restrict__ out) {
    __shared__ float bn[D_HIDC];
    int g = blockIdx.x, t = threadIdx.x;
    float s = 0.f, q = 0.f;
    for (int gg = 0; gg < N_GRAPHSC; gg++) {
        float v = pooled[gg * D_HIDC + t];
        s += v; q += v * v;
    }
    float mu = s * (1.0f / N_GRAPHSC);
    float var = q * (1.0f / N_GRAPHSC) - mu * mu;
    float inv = 1.0f / sqrtf(var + 1e-5f);
    bn[t] = (pooled[g * D_HIDC + t] - mu) * inv * gamma[t] + beta[t];
    __syncthreads();
    if (t < D_LATC) {
        float accum = fcb[t];
        for (int j = 0; j < D_HIDC; j++) accum += bn[j] * fcW[j * D_LATC + t];
        out[g * D_LATC + t] = accum;
    }
}

// ---------------- launch ----------------

extern "C" void kernel_launch(void* const* d_in, const int* in_sizes, int n_in,
                              void* d_out, int out_size, void* d_ws, size_t ws_size,
                              hipStream_t stream) {
    const float* x     = (const float*)d_in[0];
    const int*   ei    = (const int*)d_in[1];
    const int*   batch = (const int*)d_in[2];
    const float* W0 = (const float*)d_in[3];
    const float* b0 = (const float*)d_in[4];
    const float* W1 = (const float*)d_in[5];
    const float* b1 = (const float*)d_in[6];
    const float* W2 = (const float*)d_in[7];
    const float* b2 = (const float*)d_in[8];
    const float* gamma = (const float*)d_in[9];
    const float* beta  = (const float*)d_in[10];
    const float* fcW   = (const float*)d_in[11];
    const float* fcb   = (const float*)d_in[12];
    float* out = (float*)d_out;
    const int* srcv = ei;
    const int* dstv = ei + N_EDGESC;

    char* p = (char*)d_ws;
    auto alloc = [&](size_t bytes) -> char* {
        char* r = p;
        p += (bytes + 255) & ~(size_t)255;
        return r;
    };
    int*   deg_cnt = (int*)alloc((size_t)N_PAD * 4);
    int*   cursor  = (int*)alloc((size_t)N_NODESC * 4);
    float* delta_p = (float*)alloc(4);
    float* pooled  = (float*)alloc((size_t)N_GRAPHSC * D_HIDC * 4);
    char*  zero_end = p;
    int*   row_off = (int*)alloc((size_t)(N_NODESC + 1) * 4);
    int*   goff    = (int*)alloc((size_t)(N_GRAPHSC + 1) * 4);
    int*   bsum    = (int*)alloc(256 * 4);
    float* lsum    = (float*)alloc(256 * 4);
    float2* amat   = (float2*)alloc((size_t)N_PAD * 8);              // 400 KB
    int*   csr_src = (int*)alloc((size_t)N_EDGESC * 4);
    u16*   Wt      = (u16*)alloc((size_t)3 * D_WROW * D_HIDC * 2);   // 1.28 MB
    u16*   hA      = (u16*)alloc((size_t)N_PAD * D_HIDC * 2);        // 12.8 MB
    u16*   hB      = (u16*)alloc((size_t)N_PAD * D_HIDC * 2);        // 12.8 MB
    u16*   G       = (u16*)alloc((size_t)N_PAD * D_GS * 2);          // 51.2 MB

    int nz = (int)((zero_end - (char*)deg_cnt) / 4);
    int ZB = (nz + 255) / 256;
    int setup_grid = ZB + 12500 + 78 + 1;
    k_setup<<<setup_grid, 256, 0, stream>>>(x, W0, W1, W2, batch,
                                            hB, Wt, deg_cnt, nz, ZB, goff);
    k_count<<<(N_EDGESC + 255) / 256, 256, 0, stream>>>(dstv, deg_cnt);
    k_scan_part<<<196, 256, 0, stream>>>(deg_cnt, bsum, lsum);
    k_scan_block<<<1, 256, 0, stream>>>(bsum, lsum, delta_p);
    k_scan_final<<<196, 256, 0, stream>>>(deg_cnt, bsum, delta_p, row_off, amat);
    k_fill_csr<<<(N_EDGESC + 255) / 256, 256, 0, stream>>>(srcv, dstv, row_off, cursor, csr_src);

    const float* bs[3] = {b0, b1, b2};
    const u16* h_in[3]  = {hB, hA, hB};
    u16*       h_out[3] = {hA, hB, hA};
    size_t wsz = (size_t)D_WROW * D_HIDC;
    for (int l = 0; l < 3; l++) {
        k_aggregate<<<(N_NODESC + 7) / 8, 256, 0, stream>>>(
            h_in[l], row_off, csr_src, G);
        k_gemm<<<(N_PAD / 128) * 2, 256, 0, stream>>>(
            h_in[l], G, Wt + (size_t)l * wsz, amat, bs[l], h_out[l]);
    }
    k_pool<<<4 * N_GRAPHSC, 256, 0, stream>>>(h_out[2], goff, pooled);
    k_bn_fc<<<N_GRAPHSC, 128, 0, stream>>>(pooled, gamma, beta, fcW, fcb, out);
}

// Round 14
// 376.086 us; speedup vs baseline: 1.0801x; 1.0801x over previous
//
#include <hip/hip_runtime.h>
#include <cstdint>
#include <cstddef>

#define N_NODESC 50000
#define N_PAD    50048   // 391 * 128
#define N_EDGESC 600000
#define N_GRAPHSC 64
#define D_HIDC   128
#define D_LATC   64
#define D_GS     512     // G = [mean, max, min, std] (h section read from h directly)
#define D_WROW   1664    // transposed W row length (13*128)

typedef unsigned short u16;
typedef unsigned int   u32;

typedef _Float16 f16x8 __attribute__((ext_vector_type(8)));
typedef _Float16 f16x2 __attribute__((ext_vector_type(2)));
typedef float    f32x4 __attribute__((ext_vector_type(4)));
typedef float    f32x2 __attribute__((ext_vector_type(2)));

__device__ __forceinline__ u16 f2h(float f) {
    return __builtin_bit_cast(u16, (_Float16)f);
}
__device__ __forceinline__ float h2f(u16 u) {
    return (float)__builtin_bit_cast(_Float16, u);
}
__device__ __forceinline__ u32 pkrtz(float a, float b) {
    return __builtin_bit_cast(u32, __builtin_amdgcn_cvt_pkrtz(a, b));
}

// packed f32 ops (force v_pk_* codegen; pure-VALU asm, no ordering hazard)
__device__ __forceinline__ f32x2 pk_add(f32x2 a, f32x2 b) {
    f32x2 d;
    asm("v_pk_add_f32 %0, %1, %2" : "=v"(d) : "v"(a), "v"(b));
    return d;
}
__device__ __forceinline__ f32x2 pk_fma(f32x2 a, f32x2 b, f32x2 c) {
    f32x2 d;
    asm("v_pk_fma_f32 %0, %1, %2, %3" : "=v"(d) : "v"(a), "v"(b), "v"(c));
    return d;
}

__device__ __forceinline__ void gll16(void* lds, const void* g) {
    // async global->LDS, 16B per lane; HW dest = wave-uniform base + lane*16
    __builtin_amdgcn_global_load_lds(
        (const __attribute__((address_space(1))) void*)g,
        (__attribute__((address_space(3))) void*)lds, 16, 0, 0);
}

// ---------------- fused setup ----------------
// block ranges: [0,ZB) zero | [ZB,ZB+12500) x2h | next 78 wconv(LDS) | last goff
__global__ void __launch_bounds__(256) k_setup(
        const float* __restrict__ x, const float* __restrict__ W0,
        const float* __restrict__ W1, const float* __restrict__ W2,
        const int* __restrict__ batch,
        u16* __restrict__ h, u16* __restrict__ Wt,
        int* __restrict__ zero_base, int nz, int ZB, int* __restrict__ goff) {
    __shared__ u16 lt[64 * 128];   // 16 KB transpose tile (wconv blocks only)
    int b = blockIdx.x;
    int t = threadIdx.x;
    if (b < ZB) {
        int i = b * 256 + t;
        if (i < nz) zero_base[i] = 0;
        return;
    }
    b -= ZB;
    if (b < 12500) {                       // x -> fp16 (2 elems/thread)
        int i = b * 256 + t;
        float2 v = ((const float2*)x)[i];
        ((u32*)h)[i] = (u32)f2h(v.x) | ((u32)f2h(v.y) << 16);
        return;
    }
    b -= 12500;
    if (b < 78) {                          // W transpose+cast, LDS-tiled
        int which = b / 26;
        int k0 = (b % 26) * 64;
        const float* W = (which == 0) ? W0 : (which == 1) ? W1 : W2;
        const float* src = W + (size_t)k0 * D_HIDC;
        for (int i = t; i < 64 * 128; i += 256)
            lt[i] = f2h(src[i]);           // lt[kk*128 + j]
        __syncthreads();
        int j = t & 127, kh = t >> 7;
        u16* dst = Wt + (size_t)which * D_WROW * D_HIDC
                      + (size_t)j * D_WROW + k0 + kh * 32;
        #pragma unroll
        for (int c = 0; c < 4; c++) {
            int kb = kh * 32 + c * 8;
            u32 p0 = (u32)lt[(kb + 0) * 128 + j] | ((u32)lt[(kb + 1) * 128 + j] << 16);
            u32 p1 = (u32)lt[(kb + 2) * 128 + j] | ((u32)lt[(kb + 3) * 128 + j] << 16);
            u32 p2 = (u32)lt[(kb + 4) * 128 + j] | ((u32)lt[(kb + 5) * 128 + j] << 16);
            u32 p3 = (u32)lt[(kb + 6) * 128 + j] | ((u32)lt[(kb + 7) * 128 + j] << 16);
            uint4 v; v.x = p0; v.y = p1; v.z = p2; v.w = p3;
            *(uint4*)(dst + c * 8) = v;
        }
        return;
    }
    // goff via binary search over sorted batch
    int g = t;
    if (g <= N_GRAPHSC) {
        int lo = 0, hi = N_NODESC;
        while (lo < hi) {
            int mid = (lo + hi) >> 1;
            if (batch[mid] < g) lo = mid + 1; else hi = mid;
        }
        goff[g] = lo;
    }
}

__global__ void k_count(const int* __restrict__ dst, int* __restrict__ deg) {
    int e = blockIdx.x * 256 + threadIdx.x;
    if (e < N_EDGESC) atomicAdd(&deg[dst[e]], 1);
}

// 196 blocks: per-block int sum -> bsum, per-block logf sum -> lsum
__global__ void __launch_bounds__(256) k_scan_part(
        const int* __restrict__ deg, int* __restrict__ bsum,
        float* __restrict__ lsum) {
    __shared__ int s[256];
    __shared__ float ls[256];
    int idx = blockIdx.x * 256 + threadIdx.x;
    int v = (idx < N_NODESC) ? deg[idx] : 0;
    s[threadIdx.x] = v;
    ls[threadIdx.x] = (idx < N_NODESC) ? logf((float)v + 1.0f) : 0.0f;
    __syncthreads();
    for (int o = 128; o > 0; o >>= 1) {
        if (threadIdx.x < o) {
            s[threadIdx.x] += s[threadIdx.x + o];
            ls[threadIdx.x] += ls[threadIdx.x + o];
        }
        __syncthreads();
    }
    if (threadIdx.x == 0) { bsum[blockIdx.x] = s[0]; lsum[blockIdx.x] = ls[0]; }
}

// 1 block: exclusive-scan bsum (196 entries) + reduce lsum -> delta
__global__ void __launch_bounds__(256) k_scan_block(
        int* __restrict__ bsum, const float* __restrict__ lsum,
        float* __restrict__ delta_p) {
    __shared__ int s[256];
    __shared__ float ls[256];
    int t = threadIdx.x;
    int v = (t < 196) ? bsum[t] : 0;
    s[t] = v;
    ls[t] = (t < 196) ? lsum[t] : 0.0f;
    __syncthreads();
    for (int o = 1; o < 256; o <<= 1) {
        int add = (t >= o) ? s[t - o] : 0;
        __syncthreads();
        s[t] += add;
        __syncthreads();
    }
    if (t < 196) bsum[t] = s[t] - v;   // exclusive
    for (int o = 128; o > 0; o >>= 1) {
        if (t < o) ls[t] += ls[t + o];
        __syncthreads();
    }
    if (t == 0) delta_p[0] = ls[0] * (1.0f / (float)N_NODESC);
}

// 196 blocks: block-local exclusive scan + block offset -> row_off.
// Also emits the per-node PNA scaler table amat[n] = {am, at}
// (delta_p is ready: k_scan_block runs before this kernel).
__global__ void __launch_bounds__(256) k_scan_final(
        const int* __restrict__ deg, const int* __restrict__ bsum,
        const float* __restrict__ delta_p,
        int* __restrict__ row_off, float2* __restrict__ amat) {
    __shared__ int s[256];
    int t = threadIdx.x;
    int idx = blockIdx.x * 256 + t;
    int v = (idx < N_NODESC) ? deg[idx] : 0;
    s[t] = v; __syncthreads();
    for (int o = 1; o < 256; o <<= 1) {
        int add = (t >= o) ? s[t - o] : 0;
        __syncthreads();
        s[t] += add;
        __syncthreads();
    }
    int excl = s[t] - v + bsum[blockIdx.x];
    if (idx < N_NODESC) row_off[idx] = excl;
    if (idx == 0) row_off[N_NODESC] = N_EDGESC;
    if (idx < N_PAD) {
        float delta = delta_p[0];
        float logd = logf((float)v + 1.0f);   // v=0 for pad nodes
        float2 aa;
        aa.x = logd / delta;                   // am
        aa.y = delta / fmaxf(logd, 1e-5f);     // at (pad: large, discarded)
        amat[idx] = aa;
    }
}

// csr stores PRE-SCALED byte offsets (src*256) so gathers are base+u32 voffset
__global__ void k_fill_csr(const int* __restrict__ src, const int* __restrict__ dst,
                           const int* __restrict__ row_off, int* __restrict__ cursor,
                           int* __restrict__ csr_src) {
    int e = blockIdx.x * 256 + threadIdx.x;
    if (e < N_EDGESC) {
        int d = dst[e];
        int pos = row_off[d] + atomicAdd(&cursor[d], 1);
        csr_src[pos] = src[e] << 8;   // byte offset into h (128 * 2B per row)
    }
}

// ---------------- per-layer kernels ----------------

// R7 agg (verified best; R10 uint4-index and R11 16-lane variants both
// null/negative -> gather-completion-latency floor ~33us): one node per
// half-wave + 8-deep gather pipeline, rotated scalar index prefetch,
// packed f32 sum/sq, exact fp16 packed min/max.
__global__ void __launch_bounds__(256) k_aggregate(
        const u16* __restrict__ h, const int* __restrict__ row_off,
        const int* __restrict__ csr_src, u16* __restrict__ G) {
    int lane = threadIdx.x & 63;
    int half = lane >> 5, l32 = lane & 31;
    int n = blockIdx.x * 8 + ((threadIdx.x >> 6) << 1) + half;
    if (n >= N_NODESC) return;
    int c4 = 4 * l32;
    u32 c8 = 8u * (u32)l32;
    const char* h8 = (const char*)h;
    int beg = row_off[n], end = row_off[n + 1];
    const _Float16 NEG = (_Float16)(-65504.0f), POS = (_Float16)(65504.0f);
    f32x2 s01 = {0.f, 0.f}, s23 = {0.f, 0.f};
    f32x2 q01 = {0.f, 0.f}, q23 = {0.f, 0.f};
    f16x2 mx01 = {NEG, NEG}, mx23 = {NEG, NEG};
    f16x2 mn01 = {POS, POS}, mn23 = {POS, POS};

    #define PROC(u) { \
        f16x2 p01 = __builtin_bit_cast(f16x2, (u).x); \
        f16x2 p23 = __builtin_bit_cast(f16x2, (u).y); \
        f32x2 c01 = __builtin_convertvector(p01, f32x2); \
        f32x2 c23 = __builtin_convertvector(p23, f32x2); \
        s01 = pk_add(s01, c01); s23 = pk_add(s23, c23); \
        q01 = pk_fma(c01, c01, q01); q23 = pk_fma(c23, c23, q23); \
        mx01 = __builtin_elementwise_max(mx01, p01); \
        mx23 = __builtin_elementwise_max(mx23, p23); \
        mn01 = __builtin_elementwise_min(mn01, p01); \
        mn23 = __builtin_elementwise_min(mn23, p23); }
    #define GTH(e) (*(const uint2*)(h8 + ((e) + c8)))

    int i = beg;
    if (i + 8 <= end) {
        u32 e0 = (u32)csr_src[i],     e1 = (u32)csr_src[i + 1];
        u32 e2 = (u32)csr_src[i + 2], e3 = (u32)csr_src[i + 3];
        u32 e4 = (u32)csr_src[i + 4], e5 = (u32)csr_src[i + 5];
        u32 e6 = (u32)csr_src[i + 6], e7 = (u32)csr_src[i + 7];
        while (i + 16 <= end) {
            uint2 u0 = GTH(e0), u1 = GTH(e1), u2 = GTH(e2), u3 = GTH(e3);
            uint2 u4 = GTH(e4), u5 = GTH(e5), u6 = GTH(e6), u7 = GTH(e7);
            e0 = (u32)csr_src[i + 8];  e1 = (u32)csr_src[i + 9];
            e2 = (u32)csr_src[i + 10]; e3 = (u32)csr_src[i + 11];
            e4 = (u32)csr_src[i + 12]; e5 = (u32)csr_src[i + 13];
            e6 = (u32)csr_src[i + 14]; e7 = (u32)csr_src[i + 15];
            PROC(u0); PROC(u1); PROC(u2); PROC(u3);
            PROC(u4); PROC(u5); PROC(u6); PROC(u7);
            i += 8;
        }
        uint2 u0 = GTH(e0), u1 = GTH(e1), u2 = GTH(e2), u3 = GTH(e3);
        uint2 u4 = GTH(e4), u5 = GTH(e5), u6 = GTH(e6), u7 = GTH(e7);
        PROC(u0); PROC(u1); PROC(u2); PROC(u3);
        PROC(u4); PROC(u5); PROC(u6); PROC(u7);
        i += 8;
    }
    for (; i + 3 < end; i += 4) {
        u32 e0 = (u32)csr_src[i],     e1 = (u32)csr_src[i + 1];
        u32 e2 = (u32)csr_src[i + 2], e3 = (u32)csr_src[i + 3];
        uint2 u0 = GTH(e0), u1 = GTH(e1), u2 = GTH(e2), u3 = GTH(e3);
        PROC(u0); PROC(u1); PROC(u2); PROC(u3);
    }
    for (; i < end; ++i) {
        u32 e0 = (u32)csr_src[i];
        uint2 u0 = GTH(e0);
        PROC(u0);
    }
    #undef PROC
    #undef GTH

    int d = end - beg;
    float inv = 1.0f / fmaxf((float)d, 1.0f);
    f32x2 vinv = {inv, inv};
    f32x2 me01 = s01 * vinv, me23 = s23 * vinv;
    f32x2 qn01 = q01 * vinv, qn23 = q23 * vinv;
    f32x2 var01 = qn01 - me01 * me01;
    f32x2 var23 = qn23 - me23 * me23;
    const f32x2 z2 = {0.f, 0.f};
    var01 = __builtin_elementwise_max(var01, z2);
    var23 = __builtin_elementwise_max(var23, z2);
    float sd0 = sqrtf(var01.x + 1e-5f), sd1 = sqrtf(var01.y + 1e-5f);
    float sd2 = sqrtf(var23.x + 1e-5f), sd3 = sqrtf(var23.y + 1e-5f);

    u32 mep01 = pkrtz(me01.x, me01.y), mep23 = pkrtz(me23.x, me23.y);
    u32 sdp01 = pkrtz(sd0, sd1),       sdp23 = pkrtz(sd2, sd3);
    u32 mxb01 = __builtin_bit_cast(u32, mx01), mxb23 = __builtin_bit_cast(u32, mx23);
    u32 mnb01 = __builtin_bit_cast(u32, mn01), mnb23 = __builtin_bit_cast(u32, mn23);
    if (d == 0) { mxb01 = mxb23 = mnb01 = mnb23 = 0u; }

    u16* base = G + (size_t)n * D_GS;
    uint2 M; M.x = mep01; M.y = mep23;
    uint2 X; X.x = mxb01; X.y = mxb23;
    uint2 N_; N_.x = mnb01; N_.y = mnb23;
    uint2 S; S.x = sdp01; S.y = sdp23;
    *(uint2*)(base + c4)       = M;
    *(uint2*)(base + 128 + c4) = X;
    *(uint2*)(base + 256 + c4) = N_;
    *(uint2*)(base + 384 + c4) = S;
}

// h_out[n][j] = relu(bias + B*W1 + am*(S*W2) + at*(S*W3)) over logical B = [h|G]
// R4 structure -- FINAL (verified best across R1/R2/R5/R8/R9/R13 alternatives:
// W-direct, zero-LDS, counted-vmcnt, agg-fusion, BK-split, j-split all
// regressed or were neutral). 42us/dispatch latency plateau at 2 blocks/CU;
// (256,2) is the VGPR floor for the 128-reg acc file. PNA scalers from the
// amat table; ki<2 B-tiles from h directly; ki>=2 from 512-col G at (k0-128).
__global__ void __launch_bounds__(256, 2) k_gemm(
        const u16* __restrict__ hin, const u16* __restrict__ G,
        const u16* __restrict__ Wt,
        const float2* __restrict__ amat,
        const float* __restrict__ bias, u16* __restrict__ hout) {
    __shared__ _Float16 A1[128 * 64];   // 16 KB (W1)
    __shared__ _Float16 A2[128 * 64];   // 16 KB (W2)
    __shared__ _Float16 A3[128 * 64];   // 16 KB (W3)
    __shared__ _Float16 Bt[128 * 64];   // 16 KB (128-node B tile)
    const _Float16* Wf = (const _Float16*)Wt;
    const _Float16* Gf = (const _Float16*)G;
    const _Float16* Hf = (const _Float16*)hin;
    int n0 = blockIdx.x * 128;
    int t = threadIdx.x;
    int w = t >> 6, lane = t & 63;
    int srow8 = lane >> 3, sslot = lane & 7;
    int stg = (sslot ^ srow8) * 8;        // swizzled source chunk offset
    int q4 = lane >> 4, r16 = lane & 15;
    int sx0 = (q4 ^ (lane & 7)) * 8;
    int sx1 = ((q4 + 4) ^ (lane & 7)) * 8;
    int col = lane & 15;

    float atv[8];
    _Float16 amh[8];
    #pragma unroll
    for (int nt = 0; nt < 8; nt++) {
        float2 aa = amat[n0 + nt * 16 + col];
        amh[nt] = (_Float16)aa.x;
        atv[nt] = aa.y;
    }

    f32x4 acc[2][8], ac3[2][8];
    #pragma unroll
    for (int a = 0; a < 2; a++)
        #pragma unroll
        for (int b = 0; b < 8; b++) {
            acc[a][b] = (f32x4){0.f, 0.f, 0.f, 0.f};
            ac3[a][b] = (f32x4){0.f, 0.f, 0.f, 0.f};
        }

    for (int ki = 0; ki < 10; ki++) {
        int k0 = ki * 64;
        bool sreg = (k0 >= 128);
        __syncthreads();
        #pragma unroll
        for (int r = 0; r < 4; r++) {
            int rr = r * 4 + w;
            const _Float16* wrow = Wf + (size_t)(rr * 8 + srow8) * D_WROW;
            gll16(&A1[rr * 512], wrow + k0 + stg);
        }
        if (sreg) {
            #pragma unroll
            for (int r = 0; r < 4; r++) {
                int rr = r * 4 + w;
                const _Float16* wrow = Wf + (size_t)(rr * 8 + srow8) * D_WROW;
                gll16(&A2[rr * 512], wrow + 512 + k0 + stg);
                gll16(&A3[rr * 512], wrow + 1024 + k0 + stg);
            }
        }
        #pragma unroll
        for (int q = 0; q < 4; q++) {
            int rr = q * 4 + w;
            int row = n0 + rr * 8 + srow8;
            const _Float16* bsrc = (!sreg)
                ? Hf + (size_t)row * D_HIDC + k0 + stg
                : Gf + (size_t)row * D_GS + (k0 - 128) + stg;
            gll16(&Bt[rr * 512], bsrc);
        }
        __syncthreads();
        f16x8 a00 = *(const f16x8*)&A1[(w * 32 + r16) * 64 + sx0];
        f16x8 a01 = *(const f16x8*)&A1[(w * 32 + r16) * 64 + sx1];
        f16x8 a10 = *(const f16x8*)&A1[(w * 32 + 16 + r16) * 64 + sx0];
        f16x8 a11 = *(const f16x8*)&A1[(w * 32 + 16 + r16) * 64 + sx1];
        if (!sreg) {
            #pragma unroll
            for (int nt = 0; nt < 8; nt++) {
                f16x8 b0 = *(const f16x8*)&Bt[(nt * 16 + r16) * 64 + sx0];
                f16x8 b1 = *(const f16x8*)&Bt[(nt * 16 + r16) * 64 + sx1];
                acc[0][nt] = __builtin_amdgcn_mfma_f32_16x16x32_f16(a00, b0, acc[0][nt], 0, 0, 0);
                acc[1][nt] = __builtin_amdgcn_mfma_f32_16x16x32_f16(a10, b0, acc[1][nt], 0, 0, 0);
                acc[0][nt] = __builtin_amdgcn_mfma_f32_16x16x32_f16(a01, b1, acc[0][nt], 0, 0, 0);
                acc[1][nt] = __builtin_amdgcn_mfma_f32_16x16x32_f16(a11, b1, acc[1][nt], 0, 0, 0);
            }
        } else {
            f16x8 w2a0 = *(const f16x8*)&A2[(w * 32 + r16) * 64 + sx0];
            f16x8 w2a1 = *(const f16x8*)&A2[(w * 32 + r16) * 64 + sx1];
            f16x8 w2b0 = *(const f16x8*)&A2[(w * 32 + 16 + r16) * 64 + sx0];
            f16x8 w2b1 = *(const f16x8*)&A2[(w * 32 + 16 + r16) * 64 + sx1];
            f16x8 w3a0 = *(const f16x8*)&A3[(w * 32 + r16) * 64 + sx0];
            f16x8 w3a1 = *(const f16x8*)&A3[(w * 32 + r16) * 64 + sx1];
            f16x8 w3b0 = *(const f16x8*)&A3[(w * 32 + 16 + r16) * 64 + sx0];
            f16x8 w3b1 = *(const f16x8*)&A3[(w * 32 + 16 + r16) * 64 + sx1];
            #pragma unroll
            for (int nt = 0; nt < 8; nt++) {
                f16x8 b0 = *(const f16x8*)&Bt[(nt * 16 + r16) * 64 + sx0];
                f16x8 b1 = *(const f16x8*)&Bt[(nt * 16 + r16) * 64 + sx1];
                f16x8 bm0 = b0 * amh[nt];
                f16x8 bm1 = b1 * amh[nt];
                acc[0][nt] = __builtin_amdgcn_mfma_f32_16x16x32_f16(a00, b0, acc[0][nt], 0, 0, 0);
                acc[1][nt] = __builtin_amdgcn_mfma_f32_16x16x32_f16(a10, b0, acc[1][nt], 0, 0, 0);
                acc[0][nt] = __builtin_amdgcn_mfma_f32_16x16x32_f16(a01, b1, acc[0][nt], 0, 0, 0);
                acc[1][nt] = __builtin_amdgcn_mfma_f32_16x16x32_f16(a11, b1, acc[1][nt], 0, 0, 0);
                acc[0][nt] = __builtin_amdgcn_mfma_f32_16x16x32_f16(w2a0, bm0, acc[0][nt], 0, 0, 0);
                acc[1][nt] = __builtin_amdgcn_mfma_f32_16x16x32_f16(w2b0, bm0, acc[1][nt], 0, 0, 0);
                acc[0][nt] = __builtin_amdgcn_mfma_f32_16x16x32_f16(w2a1, bm1, acc[0][nt], 0, 0, 0);
                acc[1][nt] = __builtin_amdgcn_mfma_f32_16x16x32_f16(w2b1, bm1, acc[1][nt], 0, 0, 0);
                ac3[0][nt] = __builtin_amdgcn_mfma_f32_16x16x32_f16(w3a0, b0, ac3[0][nt], 0, 0, 0);
                ac3[1][nt] = __builtin_amdgcn_mfma_f32_16x16x32_f16(w3b0, b0, ac3[1][nt], 0, 0, 0);
                ac3[0][nt] = __builtin_amdgcn_mfma_f32_16x16x32_f16(w3a1, b1, ac3[0][nt], 0, 0, 0);
                ac3[1][nt] = __builtin_amdgcn_mfma_f32_16x16x32_f16(w3b1, b1, ac3[1][nt], 0, 0, 0);
            }
        }
    }
    // D[row=(lane>>4)*4+reg][col=lane&15]; row -> j, col -> node
    int rowq = q4 * 4;
    #pragma unroll
    for (int nt = 0; nt < 8; nt++) {
        int node = n0 + nt * 16 + col;
        float at = atv[nt];
        #pragma unroll
        for (int mt = 0; mt < 2; mt++) {
            int jb = w * 32 + mt * 16 + rowq;
            f32x4 v = acc[mt][nt], v3 = ac3[mt][nt];
            ushort4 o;
            o.x = f2h(fmaxf(v.x + at * v3.x + bias[jb], 0.0f));
            o.y = f2h(fmaxf(v.y + at * v3.y + bias[jb + 1], 0.0f));
            o.z = f2h(fmaxf(v.z + at * v3.z + bias[jb + 2], 0.0f));
            o.w = f2h(fmaxf(v.w + at * v3.w + bias[jb + 3], 0.0f));
            *(ushort4*)&hout[(size_t)node * D_HIDC + jb] = o;
        }
    }
}

// ---------------- epilogue kernels ----------------

__global__ void __launch_bounds__(256) k_pool(
        const u16* __restrict__ h, const int* __restrict__ goff,
        float* __restrict__ pooled) {
    __shared__ float sm[256];
    int g = blockIdx.x >> 2, s = blockIdx.x & 3;
    int gb = goff[g], ge = goff[g + 1];
    int len = ge - gb;
    int q = (len + 3) >> 2;
    int nb = gb + s * q;
    int ne = min(nb + q, ge);
    int t = threadIdx.x;
    int j = t & 127, half = t >> 7;
    float acc = 0.0f;
    for (int n = nb + half; n < ne; n += 2)
        acc += h2f(h[(size_t)n * D_HIDC + j]);
    sm[t] = acc; __syncthreads();
    if (t < 128) {
        float v = sm[t] + sm[t + 128];
        atomicAdd(&pooled[g * D_HIDC + j], v);
    }
}

// one block per graph; redundant mu/var recompute (pooled is tiny, L2-hot)
__global__ void __launch_bounds__(128) k_bn_fc(
        const float* __restrict__ pooled, const float* __restrict__ gamma,
        const float* __restrict__ beta, const float* __restrict__ fcW,
        const float* __restrict__ fcb, float* __restrict__ out) {
    __shared__ float bn[D_HIDC];
    int g = blockIdx.x, t = threadIdx.x;
    float s = 0.f, q = 0.f;
    for (int gg = 0; gg < N_GRAPHSC; gg++) {
        float v = pooled[gg * D_HIDC + t];
        s += v; q += v * v;
    }
    float mu = s * (1.0f / N_GRAPHSC);
    float var = q * (1.0f / N_GRAPHSC) - mu * mu;
    float inv = 1.0f / sqrtf(var + 1e-5f);
    bn[t] = (pooled[g * D_HIDC + t] - mu) * inv * gamma[t] + beta[t];
    __syncthreads();
    if (t < D_LATC) {
        float accum = fcb[t];
        for (int j = 0; j < D_HIDC; j++) accum += bn[j] * fcW[j * D_LATC + t];
        out[g * D_LATC + t] = accum;
    }
}

// ---------------- launch ----------------

extern "C" void kernel_launch(void* const* d_in, const int* in_sizes, int n_in,
                              void* d_out, int out_size, void* d_ws, size_t ws_size,
                              hipStream_t stream) {
    const float* x     = (const float*)d_in[0];
    const int*   ei    = (const int*)d_in[1];
    const int*   batch = (const int*)d_in[2];
    const float* W0 = (const float*)d_in[3];
    const float* b0 = (const float*)d_in[4];
    const float* W1 = (const float*)d_in[5];
    const float* b1 = (const float*)d_in[6];
    const float* W2 = (const float*)d_in[7];
    const float* b2 = (const float*)d_in[8];
    const float* gamma = (const float*)d_in[9];
    const float* beta  = (const float*)d_in[10];
    const float* fcW   = (const float*)d_in[11];
    const float* fcb   = (const float*)d_in[12];
    float* out = (float*)d_out;
    const int* srcv = ei;
    const int* dstv = ei + N_EDGESC;

    char* p = (char*)d_ws;
    auto alloc = [&](size_t bytes) -> char* {
        char* r = p;
        p += (bytes + 255) & ~(size_t)255;
        return r;
    };
    int*   deg_cnt = (int*)alloc((size_t)N_PAD * 4);
    int*   cursor  = (int*)alloc((size_t)N_NODESC * 4);
    float* delta_p = (float*)alloc(4);
    float* pooled  = (float*)alloc((size_t)N_GRAPHSC * D_HIDC * 4);
    char*  zero_end = p;
    int*   row_off = (int*)alloc((size_t)(N_NODESC + 1) * 4);
    int*   goff    = (int*)alloc((size_t)(N_GRAPHSC + 1) * 4);
    int*   bsum    = (int*)alloc(256 * 4);
    float* lsum    = (float*)alloc(256 * 4);
    float2* amat   = (float2*)alloc((size_t)N_PAD * 8);              // 400 KB
    int*   csr_src = (int*)alloc((size_t)N_EDGESC * 4);
    u16*   Wt      = (u16*)alloc((size_t)3 * D_WROW * D_HIDC * 2);   // 1.28 MB
    u16*   hA      = (u16*)alloc((size_t)N_PAD * D_HIDC * 2);        // 12.8 MB
    u16*   hB      = (u16*)alloc((size_t)N_PAD * D_HIDC * 2);        // 12.8 MB
    u16*   G       = (u16*)alloc((size_t)N_PAD * D_GS * 2);          // 51.2 MB

    int nz = (int)((zero_end - (char*)deg_cnt) / 4);
    int ZB = (nz + 255) / 256;
    int setup_grid = ZB + 12500 + 78 + 1;
    k_setup<<<setup_grid, 256, 0, stream>>>(x, W0, W1, W2, batch,
                                            hB, Wt, deg_cnt, nz, ZB, goff);
    k_count<<<(N_EDGESC + 255) / 256, 256, 0, stream>>>(dstv, deg_cnt);
    k_scan_part<<<196, 256, 0, stream>>>(deg_cnt, bsum, lsum);
    k_scan_block<<<1, 256, 0, stream>>>(bsum, lsum, delta_p);
    k_scan_final<<<196, 256, 0, stream>>>(deg_cnt, bsum, delta_p, row_off, amat);
    k_fill_csr<<<(N_EDGESC + 255) / 256, 256, 0, stream>>>(srcv, dstv, row_off, cursor, csr_src);

    const float* bs[3] = {b0, b1, b2};
    const u16* h_in[3]  = {hB, hA, hB};
    u16*       h_out[3] = {hA, hB, hA};
    size_t wsz = (size_t)D_WROW * D_HIDC;
    for (int l = 0; l < 3; l++) {
        k_aggregate<<<(N_NODESC + 7) / 8, 256, 0, stream>>>(
            h_in[l], row_off, csr_src, G);
        k_gemm<<<N_PAD / 128, 256, 0, stream>>>(
            h_in[l], G, Wt + (size_t)l * wsz, amat, bs[l], h_out[l]);
    }
    k_pool<<<4 * N_GRAPHSC, 256, 0, stream>>>(h_out[2], goff, pooled);
    k_bn_fc<<<N_GRAPHSC, 128, 0, stream>>>(pooled, gamma, beta, fcW, fcb, out);
}